// Round 4
// baseline (10.935 us; speedup 1.0000x reference)
//
#include <hip/hip_runtime.h>
#include <hip/hip_bf16.h>

#define BT_DEPTH 20
#define BT_NDIMS 128

// Row-local shift-right add via DPP row_shr (0-filled at row boundary,
// bound_ctrl=true). After ctrl 0x111,0x112,0x114,0x118 lane (row*16+15)
// holds the 16-lane row sum. dpp_ctrl must be a compile-time constant ->
// template parameter.
template <int CTRL>
__device__ __forceinline__ float dpp_row_shr_add(float v) {
    int sh = __builtin_amdgcn_update_dpp(0, __float_as_int(v), CTRL, 0xF, 0xF, true);
    return v + __int_as_float(sh);
}

// ONE wave (64 threads). lane = g*16 + d: g = level-group (4 levels in flight),
// d = dim-chunk (8 dims each, 16 chunks = 128 dims). 6 iterations cover levels
// l = 4i + g for l <= 20. No LDS, no barriers. Product of sigmoids computed as
// 1 / prod(1 + exp(-z)) with the factors distributed over the 4 leader lanes.
__global__ __launch_bounds__(64) void BinaryTree_18734647345500_kernel(
    const float* __restrict__ W,
    const int* __restrict__ v_j_idx,
    const int* __restrict__ u_k_idx,
    float* __restrict__ out)
{
    const int lane = threadIdx.x;
    const int g    = lane >> 4;   // 0..3  level group
    const int d    = lane & 15;   // 0..15 dim chunk (8 floats)

    const int v = v_j_idx[0];
    const int u = u_k_idx[0];

    const long long leaf = (long long)v + ((1 << BT_DEPTH) - 1);
    const unsigned  t    = (unsigned)u + (1u << BT_DEPTH);

    // This lane's 8 dims of x.
    const float* xrow = W + leaf * BT_NDIMS + d * 8;
    const float4 x0 = *(const float4*)(xrow);
    const float4 x1 = *(const float4*)(xrow + 4);

    float qp = 1.0f;  // product of (1 + exp(-z_l)) for this leader lane's levels

    #pragma unroll
    for (int i = 0; i < 6; ++i) {
        const int l = i * 4 + g;
        if (l <= BT_DEPTH) {
            const long long node = (long long)(t >> (BT_DEPTH - l)) - 1;
            const float* row = W + node * (long long)BT_NDIMS + d * 8;
            const float4 r0 = *(const float4*)(row);
            const float4 r1 = *(const float4*)(row + 4);
            float s = r0.x * x0.x + r0.y * x0.y + r0.z * x0.z + r0.w * x0.w
                    + r1.x * x1.x + r1.y * x1.y + r1.z * x1.z + r1.w * x1.w;
            // 16-lane row reduction, 4-deep VALU chain.
            s = dpp_row_shr_add<0x111>(s);  // row_shr:1
            s = dpp_row_shr_add<0x112>(s);  // row_shr:2
            s = dpp_row_shr_add<0x114>(s);  // row_shr:4
            s = dpp_row_shr_add<0x118>(s);  // row_shr:8
            // lane d==15 holds z_l; others hold partials (harmless).
            const float q = 1.0f + __expf(-s);
            if (d == 15) qp *= q;
        }
    }

    // Combine the 4 leader lanes' partial products (uniform broadcasts).
    const float r15 = __uint_as_float(__builtin_amdgcn_readlane(__float_as_uint(qp), 15));
    const float r31 = __uint_as_float(__builtin_amdgcn_readlane(__float_as_uint(qp), 31));
    const float r47 = __uint_as_float(__builtin_amdgcn_readlane(__float_as_uint(qp), 47));
    const float r63 = __uint_as_float(__builtin_amdgcn_readlane(__float_as_uint(qp), 63));

    if (lane == 0) {
        out[0] = 1.0f / (r15 * r31 * r47 * r63);
    }
}

extern "C" void kernel_launch(void* const* d_in, const int* in_sizes, int n_in,
                              void* d_out, int out_size, void* d_ws, size_t ws_size,
                              hipStream_t stream) {
    const float* W   = (const float*)d_in[0];
    const int*   vj  = (const int*)d_in[1];
    const int*   uk  = (const int*)d_in[2];
    float*       out = (float*)d_out;

    hipLaunchKernelGGL(BinaryTree_18734647345500_kernel,
                       dim3(1), dim3(64), 0, stream,
                       W, vj, uk, out);
}